// Round 1
// baseline (39.696 us; speedup 1.0000x reference)
//
#include <hip/hip_runtime.h>

#define INF_VAL 100000000.0f

#define N0 65536
#define N1 32768
#define N2 16384
#define NTOT (N0 + N1 + N2)
#define M_ANN 512

__global__ __launch_bounds__(256) void assign_anchors_kernel(
    const float* __restrict__ ann,   // [512,3] (l, r, c)
    const float* __restrict__ a0,    // [65536]
    const float* __restrict__ a1,    // [32768]
    const float* __restrict__ a2,    // [16384]
    float* __restrict__ out)         // [12 * NTOT]
{
    const int g = blockIdx.x * 256 + threadIdx.x;

    // Block-uniform level resolution (each block lies entirely in one level).
    int level, local;
    const float* __restrict__ anch;
    if (g < N0)            { level = 0; local = g;           anch = a0; }
    else if (g < N0 + N1)  { level = 1; local = g - N0;      anch = a1; }
    else                   { level = 2; local = g - N0 - N1; anch = a2; }

    const float stride = (float)(1 << level);
    const float inv_stride = 1.0f / stride;   // stride is 1/2/4: exact

    // Thresholds: replicate JAX weak-type promotion — double product, cast to f32.
    const double TR = 22050.0 / 256.0;        // 86.1328125
    float lo_t, hi_t;
    if (level == 0)      { lo_t = (float)(-1.0  * TR); hi_t = (float)(0.45   * TR); }
    else if (level == 1) { lo_t = (float)(0.45  * TR); hi_t = (float)(0.9    * TR); }
    else                 { lo_t = (float)(0.9   * TR); hi_t = (float)(1000.0 * TR); }

    // Stage annotations: (l, r, radius_limit, area) + class.
    __shared__ float4 s_ann[M_ANN];
    __shared__ float  s_c[M_ANN];
    for (int j = threadIdx.x; j < M_ANN; j += 256) {
        float l = ann[j * 3 + 0];
        float r = ann[j * 3 + 1];
        float c = ann[j * 3 + 2];
        float radius = (c == 0.0f) ? 4.5f : ((c == 1.0f) ? 2.5f : 0.0f);
        float rl = l + radius * stride;       // radius_limit
        s_ann[j] = make_float4(l, r, rl, r - l);
        s_c[j] = c;
    }
    __syncthreads();

    const float a = anch[local];

    // First-occurrence argmin over masked areas (matches jnp.argmin semantics:
    // strict < keeps the earliest minimal index; all-INF case leaves idx=0).
    float best = INF_VAL;
    int bidx = 0;
    #pragma unroll 8
    for (int j = 0; j < M_ANN; ++j) {
        float4 v = s_ann[j];                  // wave-uniform addr -> LDS broadcast
        bool valid = (a >= v.x) & (a <= fminf(v.y, v.z));
        float lsj = a - v.x;
        float rsj = v.y - a;
        float m = fmaxf(lsj, rsj);
        valid = valid & (m >= lo_t) & (m <= hi_t);
        float val = valid ? v.w : INF_VAL;
        if (val < best) { best = val; bidx = j; }
    }

    const float4 w = s_ann[bidx];
    const float l = w.x;
    const float r = w.y;
    const bool pos = (best != INF_VAL);
    const float cc = pos ? s_c[bidx] : 0.0f;
    const float ls = a - l;
    const float rs = r - a;

    // Outputs (per-field, concatenated across levels; g is the global anchor idx).
    out[g]                    = pos ? 1.0f : 0.0f;        // pos
    out[NTOT     + g * 3 + 0] = l;                        // assigned
    out[NTOT     + g * 3 + 1] = r;
    out[NTOT     + g * 3 + 2] = cc;
    out[4 * NTOT + g * 3 + 0] = l * inv_stride;           // normalized
    out[4 * NTOT + g * 3 + 1] = r * inv_stride;
    out[4 * NTOT + g * 3 + 2] = cc;
    out[7 * NTOT  + g] = ls;                              // l_star
    out[8 * NTOT  + g] = rs;                              // r_star
    out[9 * NTOT  + g] = ls * inv_stride;                 // nl_star
    out[10 * NTOT + g] = rs * inv_stride;                 // nr_star
    out[11 * NTOT + g] = (float)(level + 1);              // levels
}

extern "C" void kernel_launch(void* const* d_in, const int* in_sizes, int n_in,
                              void* d_out, int out_size, void* d_ws, size_t ws_size,
                              hipStream_t stream) {
    const float* ann = (const float*)d_in[0];
    const float* a0  = (const float*)d_in[1];
    const float* a1  = (const float*)d_in[2];
    const float* a2  = (const float*)d_in[3];
    float* out = (float*)d_out;

    const int blocks = NTOT / 256;  // 448
    assign_anchors_kernel<<<blocks, 256, 0, stream>>>(ann, a0, a1, a2, out);
}

// Round 2
// 10.187 us; speedup vs baseline: 3.8968x; 3.8968x over previous
//
#include <hip/hip_runtime.h>

#define INF_VAL 100000000.0f

#define N0 65536
#define N1 32768
#define N2 16384
#define NTOT (N0 + N1 + N2)
#define M_ANN 512

__global__ __launch_bounds__(256) void assign_anchors_kernel(
    const float* __restrict__ ann,   // [512,3] (l, r, c)
    const float* __restrict__ a0,    // [65536]
    const float* __restrict__ a1,    // [32768]
    const float* __restrict__ a2,    // [16384]
    float* __restrict__ out)         // [12 * NTOT]
{
    const int g = blockIdx.x * 256 + threadIdx.x;

    // Block-uniform level resolution (each block lies entirely in one level).
    int level, local;
    const float* __restrict__ anch;
    if (g < N0)            { level = 0; local = g;           anch = a0; }
    else if (g < N0 + N1)  { level = 1; local = g - N0;      anch = a1; }
    else                   { level = 2; local = g - N0 - N1; anch = a2; }

    const float stride = (float)(1 << level);
    const float inv_stride = 1.0f / stride;   // stride is 1/2/4: exact

    // Thresholds: replicate JAX weak-type promotion — double product, cast to f32.
    const double TR = 22050.0 / 256.0;        // 86.1328125
    float lo_t, hi_t;
    if (level == 0)      { lo_t = (float)(-1.0  * TR); hi_t = (float)(0.45   * TR); }
    else if (level == 1) { lo_t = (float)(0.45  * TR); hi_t = (float)(0.9    * TR); }
    else                 { lo_t = (float)(0.9   * TR); hi_t = (float)(1000.0 * TR); }

    // Stage annotations split into l / r / c arrays (starts are sorted).
    __shared__ float s_l[M_ANN];
    __shared__ float s_r[M_ANN];
    __shared__ float s_c[M_ANN];
    for (int j = threadIdx.x; j < M_ANN; j += 256) {
        s_l[j] = ann[j * 3 + 0];
        s_r[j] = ann[j * 3 + 1];
        s_c[j] = ann[j * 3 + 2];
    }
    __syncthreads();

    const float a = anch[local];

    // Any valid annotation j satisfies l_j <= a <= l_j + radius_j*stride with
    // radius_j*stride <= 4.5*4 = 18, so l_j in [a-18, a]. Use a conservative
    // window [a-20, a]; every candidate is re-tested with the EXACT reference
    // conditions below, so conservative bounds cannot change the result.
    const float lb = a - 20.0f;

    // Branchless lower_bound over the 512 sorted starts (9 fixed steps).
    int jlo = 0;
    #pragma unroll
    for (int step = 256; step >= 1; step >>= 1) {
        if (s_l[jlo + step - 1] < lb) jlo += step;   // may end 1 short of true
    }                                                // lower bound: harmless

    // First-occurrence argmin over masked areas within the window.
    float best = INF_VAL;
    int bidx = 0;
    for (int j = jlo; j < M_ANN; ++j) {
        float l = s_l[j];
        if (l > a) break;                            // sorted: no more candidates
        float r = s_r[j];
        float c = s_c[j];
        float radius = (c == 0.0f) ? 4.5f : ((c == 1.0f) ? 2.5f : 0.0f);
        float ub = fminf(r, l + radius * stride);    // min(r, radius_limit)
        float m = fmaxf(a - l, r - a);
        bool valid = (a >= l) & (a <= ub) & (m >= lo_t) & (m <= hi_t);
        float area = r - l;
        if (valid && (area < best)) { best = area; bidx = j; }
    }

    const float l = s_l[bidx];
    const float r = s_r[bidx];
    const bool pos = (best != INF_VAL);
    const float cc = pos ? s_c[bidx] : 0.0f;
    const float ls = a - l;
    const float rs = r - a;

    // Outputs (per-field, concatenated across levels; g is the global anchor idx).
    out[g]                    = pos ? 1.0f : 0.0f;        // pos
    out[NTOT     + g * 3 + 0] = l;                        // assigned
    out[NTOT     + g * 3 + 1] = r;
    out[NTOT     + g * 3 + 2] = cc;
    out[4 * NTOT + g * 3 + 0] = l * inv_stride;           // normalized
    out[4 * NTOT + g * 3 + 1] = r * inv_stride;
    out[4 * NTOT + g * 3 + 2] = cc;
    out[7 * NTOT  + g] = ls;                              // l_star
    out[8 * NTOT  + g] = rs;                              // r_star
    out[9 * NTOT  + g] = ls * inv_stride;                 // nl_star
    out[10 * NTOT + g] = rs * inv_stride;                 // nr_star
    out[11 * NTOT + g] = (float)(level + 1);              // levels
}

extern "C" void kernel_launch(void* const* d_in, const int* in_sizes, int n_in,
                              void* d_out, int out_size, void* d_ws, size_t ws_size,
                              hipStream_t stream) {
    const float* ann = (const float*)d_in[0];
    const float* a0  = (const float*)d_in[1];
    const float* a1  = (const float*)d_in[2];
    const float* a2  = (const float*)d_in[3];
    float* out = (float*)d_out;

    const int blocks = NTOT / 256;  // 448
    assign_anchors_kernel<<<blocks, 256, 0, stream>>>(ann, a0, a1, a2, out);
}